// Round 27
// baseline (278.278 us; speedup 1.0000x reference)
//
#include <hip/hip_runtime.h>
#include <hip/hip_bf16.h>
#include <math.h>
#include <stdint.h>

#define B_   4
#define T_   2048
#define D_   1024
#define QH   16
#define KVH  4
#define HD_  64
#define R_   (B_*T_)      // 8192 rows
#define DFF  2048
#define QKVW 1536         // fused q(1024) + kv(512) output width

typedef short short8 __attribute__((ext_vector_type(8)));
typedef short short4v __attribute__((ext_vector_type(4)));
typedef float f32x4 __attribute__((ext_vector_type(4)));

// native exp2 (bare v_exp_f32); guarded fallback is mathematically identical
#if __has_builtin(__builtin_amdgcn_exp2f)
#define EXP2(x) __builtin_amdgcn_exp2f(x)
#else
#define EXP2(x) __expf((x) * 0.6931471805599453f)
#endif

static __device__ __forceinline__ unsigned short f2bu(float x) {
    __hip_bfloat16 h = __float2bfloat16(x);
    return *reinterpret_cast<unsigned short*>(&h);
}
static __device__ __forceinline__ float bu2f(unsigned short u) {
    unsigned int w = ((unsigned int)u) << 16;
    return *reinterpret_cast<float*>(&w);
}

// swizzled byte offset within a 128B/row LDS tile (8-row XOR stripe)
#define KSWZ(row, cbyte) (((row) << 7) + ((cbyte) ^ (((row) & 7) << 4)))

__device__ __forceinline__ void gload_lds16(const void* g, void* l) {
    typedef __attribute__((address_space(1))) void gv_t;
    typedef __attribute__((address_space(3))) void lv_t;
    __builtin_amdgcn_global_load_lds((gv_t*)g, (lv_t*)l, 16, 0, 0);
}

// XCD-aware linear block swizzle (requires nwg % 8 == 0)
__device__ __forceinline__ int xcd_swz(int bid, int nwg) {
    int cpx = nwg >> 3;
    return (bid & 7) * cpx + (bid >> 3);
}

// fast GELU (tanh form) in exp2 domain
__device__ __forceinline__ float gelu_fast(float x) {
    float g2 = 2.3024523389544817f * (x + 0.044715f * x * x * x);
    return x / (1.0f + EXP2(-g2));
}

// ---------------- prologue: weight casts (blocks [0,6656)) + LN1 (blocks [6656,14848)) --------
__global__ __launch_bounds__(256) void prologue_cast_ln(const float* __restrict__ Wq,
                                                        const float* __restrict__ Wkv,
                                                        const float* __restrict__ Wo,
                                                        const float* __restrict__ W1,
                                                        const float* __restrict__ W2,
                                                        __hip_bfloat16* __restrict__ dqkv,
                                                        __hip_bfloat16* __restrict__ dWo,
                                                        __hip_bfloat16* __restrict__ dW1,
                                                        __hip_bfloat16* __restrict__ dW2,
                                                        const float* __restrict__ x,
                                                        const float* __restrict__ g,
                                                        const float* __restrict__ bta,
                                                        __hip_bfloat16* __restrict__ hb) {
    int tid = threadIdx.x;
    if (blockIdx.x < 6656) {
        int i = blockIdx.x * 256 + tid;   // quad index, total exactly 6656*256 = 1703936
        const float* src; __hip_bfloat16* dst; int off;
        if (i < 262144)       { src = Wq;  dst = dqkv;            off = i; }
        else if (i < 393216)  { src = Wkv; dst = dqkv + 1048576;  off = i - 262144; }
        else if (i < 655360)  { src = Wo;  dst = dWo;             off = i - 393216; }
        else if (i < 1179648) { src = W1;  dst = dW1;             off = i - 655360; }
        else                  { src = W2;  dst = dW2;             off = i - 1179648; }
        float4 v = *(const float4*)&src[(size_t)off*4];
        ushort4 o = { f2bu(v.x), f2bu(v.y), f2bu(v.z), f2bu(v.w) };
        *(ushort4*)&dst[(size_t)off*4] = o;
        return;
    }
    int row = blockIdx.x - 6656;
    const float* xr = x + (size_t)row * D_;
    int c = tid * 4;
    float4 v = *(const float4*)&xr[c];
    float s = v.x + v.y + v.z + v.w;
#pragma unroll
    for (int off = 32; off >= 1; off >>= 1) s += __shfl_xor(s, off);
    __shared__ float sm[4], sv[4];
    int wid = tid >> 6, lane = tid & 63;
    if (lane == 0) sm[wid] = s;
    __syncthreads();
    float mean = (sm[0] + sm[1] + sm[2] + sm[3]) * (1.0f / D_);
    float d0 = v.x - mean, d1 = v.y - mean, d2 = v.z - mean, d3 = v.w - mean;
    float qq = d0*d0 + d1*d1 + d2*d2 + d3*d3;
#pragma unroll
    for (int off = 32; off >= 1; off >>= 1) qq += __shfl_xor(qq, off);
    if (lane == 0) sv[wid] = qq;
    __syncthreads();
    float var = (sv[0] + sv[1] + sv[2] + sv[3]) * (1.0f / D_);
    float rstd = rsqrtf(var + 1e-5f);
    float4 gg = *(const float4*)&g[c];
    float4 bb = *(const float4*)&bta[c];
    ushort4 o = { f2bu(d0 * rstd * gg.x + bb.x),
                  f2bu(d1 * rstd * gg.y + bb.y),
                  f2bu(d2 * rstd * gg.z + bb.z),
                  f2bu(d3 * rstd * gg.w + bb.w) };
    *(ushort4*)&(hb + (size_t)row * D_)[c] = o;
}

// ---------------- LayerNorm with bf16 input -> bf16 out: one block per row ----------------
__global__ __launch_bounds__(256) void ln_bf16_in(const __hip_bfloat16* __restrict__ x,
                                                  const float* __restrict__ g,
                                                  const float* __restrict__ bta,
                                                  __hip_bfloat16* __restrict__ out) {
    int row = blockIdx.x;
    int tid = threadIdx.x;
    const __hip_bfloat16* xr = x + (size_t)row * D_;
    int c = tid * 4;
    ushort4 u = *(const ushort4*)&xr[c];
    float v0 = bu2f(u.x), v1 = bu2f(u.y), v2 = bu2f(u.z), v3 = bu2f(u.w);
    float s = v0 + v1 + v2 + v3;
#pragma unroll
    for (int off = 32; off >= 1; off >>= 1) s += __shfl_xor(s, off);
    __shared__ float sm[4], sv[4];
    int wid = tid >> 6, lane = tid & 63;
    if (lane == 0) sm[wid] = s;
    __syncthreads();
    float mean = (sm[0] + sm[1] + sm[2] + sm[3]) * (1.0f / D_);
    float d0 = v0 - mean, d1 = v1 - mean, d2 = v2 - mean, d3 = v3 - mean;
    float qq = d0*d0 + d1*d1 + d2*d2 + d3*d3;
#pragma unroll
    for (int off = 32; off >= 1; off >>= 1) qq += __shfl_xor(qq, off);
    if (lane == 0) sv[wid] = qq;
    __syncthreads();
    float var = (sv[0] + sv[1] + sv[2] + sv[3]) * (1.0f / D_);
    float rstd = rsqrtf(var + 1e-5f);
    float4 gg = *(const float4*)&g[c];
    float4 bb = *(const float4*)&bta[c];
    ushort4 o = { f2bu(d0 * rstd * gg.x + bb.x),
                  f2bu(d1 * rstd * gg.y + bb.y),
                  f2bu(d2 * rstd * gg.z + bb.z),
                  f2bu(d3 * rstd * gg.w + bb.w) };
    *(ushort4*)&(out + (size_t)row * D_)[c] = o;
}

// ---------------- bf16 MFMA GEMM, BK=64, swizzled LDS, 8 waves (wave-tile 64x32) --------------
// MODE 1: += res(f32), out bf16 Cb; MODE 2: += bias, gelu, out bf16 Cb;
// MODE 3: += bias, += resb(bf16), out f32 Cf
template<int MODE>
__global__ __launch_bounds__(512) void gemm_mfma(const __hip_bfloat16* __restrict__ A,
                                                 const __hip_bfloat16* __restrict__ W,
                                                 const float* __restrict__ bias,
                                                 const float* __restrict__ res,
                                                 const __hip_bfloat16* __restrict__ resb,
                                                 float* __restrict__ Cf,
                                                 __hip_bfloat16* __restrict__ Cb,
                                                 int M, int N, int K) {
    __shared__ __hip_bfloat16 At[128*64];
    __shared__ __hip_bfloat16 Bt[128*64];
    int tid = threadIdx.x;
    int w = tid >> 6, lane = tid & 63;        // w in 0..7
    int l15 = lane & 15, lhi = lane >> 4;
    int swz = xcd_swz(blockIdx.x, gridDim.x);
    int gx = N >> 7;
    int bn = (swz % gx) * 128, bm = (swz / gx) * 128;
    int wr = w >> 2, wc = w & 3;              // wave tile 64(M) x 32(N)
    f32x4 acc[4][2] = {};

    for (int k0 = 0; k0 < K; k0 += 64) {
#pragma unroll
        for (int iss = 0; iss < 2; ++iss) {
            int idx = iss*512 + tid;               // 0..1023
            int row = idx >> 3;                    // 0..127
            int cb  = (idx & 7) * 16;              // byte col within 128B row
            int sce = (cb ^ ((row & 7) << 4)) >> 1;  // pre-swizzled source col (elements)
            int ldso = idx * 16;                   // linear LDS byte offset
            gload_lds16(A + (size_t)(bm + row) * K + k0 + sce, (char*)At + ldso);
            gload_lds16(W + (size_t)(bn + row) * K + k0 + sce, (char*)Bt + ldso);
        }
        __syncthreads();
#pragma unroll
        for (int kk = 0; kk < 2; ++kk) {
            short8 af[4], bf[2];
#pragma unroll
            for (int m = 0; m < 4; ++m)
                af[m] = *(const short8*)((char*)At + KSWZ(wr*64 + m*16 + l15, kk*64 + lhi*16));
#pragma unroll
            for (int n = 0; n < 2; ++n)
                bf[n] = *(const short8*)((char*)Bt + KSWZ(wc*32 + n*16 + l15, kk*64 + lhi*16));
#pragma unroll
            for (int m = 0; m < 4; ++m)
#pragma unroll
                for (int n = 0; n < 2; ++n)
                    acc[m][n] = __builtin_amdgcn_mfma_f32_16x16x32_bf16(af[m], bf[n], acc[m][n], 0, 0, 0);
        }
        __syncthreads();
    }

#pragma unroll
    for (int m = 0; m < 4; ++m) {
#pragma unroll
        for (int j = 0; j < 4; ++j) {
            int row = bm + wr*64 + m*16 + lhi*4 + j;
#pragma unroll
            for (int n = 0; n < 2; ++n) {
                int col = bn + wc*32 + n*16 + l15;
                float val = acc[m][n][j];
                if (MODE == 2 || MODE == 3) val += bias[col];
                if (MODE == 2) val = gelu_fast(val);
                if (MODE == 1) val += res[(size_t)row * N + col];
                if (MODE == 3) val += bu2f(*(const unsigned short*)&resb[(size_t)row * N + col]);
                if (MODE == 3) Cf[(size_t)row * N + col] = val;
                else           Cb[(size_t)row * N + col] = __float2bfloat16(val);
            }
        }
    }
}

// ---------------- QKV GEMM with fused RoPE epilogue (8 waves, wave-tile 64x32) ----------------
// q is pre-scaled by (1/8)*log2e so attention scores land in the exp2 domain.
__global__ __launch_bounds__(512) void gemm_qkv_rope(const __hip_bfloat16* __restrict__ A,
                                                     const __hip_bfloat16* __restrict__ W,
                                                     const float* __restrict__ cosb,
                                                     const float* __restrict__ sinb,
                                                     __hip_bfloat16* __restrict__ qb,
                                                     __hip_bfloat16* __restrict__ kbb,
                                                     __hip_bfloat16* __restrict__ vbt) {
    const int K = D_;
    const float QS = 0.125f * 1.4426950408889634f;
    __shared__ __hip_bfloat16 At[128*64];
    __shared__ __hip_bfloat16 Bt[128*64];
    int tid = threadIdx.x;
    int w = tid >> 6, lane = tid & 63;        // w in 0..7
    int l15 = lane & 15, lhi = lane >> 4;
    int swz = xcd_swz(blockIdx.x, gridDim.x);
    const int gx = QKVW >> 7;   // 12
    int bn = (swz % gx) * 128, bm = (swz / gx) * 128;
    int wr = w >> 2, wc = w & 3;              // wave tile 64(M) x 32(N)
    f32x4 acc[4][2] = {};

    for (int k0 = 0; k0 < K; k0 += 64) {
#pragma unroll
        for (int iss = 0; iss < 2; ++iss) {
            int idx = iss*512 + tid;
            int row = idx >> 3;
            int cb  = (idx & 7) * 16;
            int sce = (cb ^ ((row & 7) << 4)) >> 1;
            int ldso = idx * 16;
            gload_lds16(A + (size_t)(bm + row) * K + k0 + sce, (char*)At + ldso);
            gload_lds16(W + (size_t)(bn + row) * K + k0 + sce, (char*)Bt + ldso);
        }
        __syncthreads();
#pragma unroll
        for (int kk = 0; kk < 2; ++kk) {
            short8 af[4], bf[2];
#pragma unroll
            for (int m = 0; m < 4; ++m)
                af[m] = *(const short8*)((char*)At + KSWZ(wr*64 + m*16 + l15, kk*64 + lhi*16));
#pragma unroll
            for (int n = 0; n < 2; ++n)
                bf[n] = *(const short8*)((char*)Bt + KSWZ(wc*32 + n*16 + l15, kk*64 + lhi*16));
#pragma unroll
            for (int m = 0; m < 4; ++m)
#pragma unroll
                for (int n = 0; n < 2; ++n)
                    acc[m][n] = __builtin_amdgcn_mfma_f32_16x16x32_bf16(af[m], bf[n], acc[m][n], 0, 0, 0);
        }
        __syncthreads();
    }

    bool is_q = (bn < 1024);
    bool is_v = (!is_q) && (wc >= 2);   // wave-uniform (v = upper 64 cols of kv tile)
    if (!is_v) {
#pragma unroll
        for (int m = 0; m < 4; ++m) {
#pragma unroll
            for (int j = 0; j < 4; ++j) {
                int row = bm + wr*64 + m*16 + lhi*4 + j;
                int b = row >> 11, t = row & (T_ - 1);
                const float* crow = cosb + t*HD_;
                const float* srow = sinb + t*HD_;
#pragma unroll
                for (int n = 0; n < 2; ++n) {
                    int col = bn + wc*32 + n*16 + l15;
                    float val = acc[m][n][j];
                    float part = __shfl_xor(val, 1);
                    float rot = (l15 & 1) ? part : -part;
                    if (is_q) {
                        int hd = col & 63;
                        float o = val * crow[hd] + rot * srow[hd];
                        int h = col >> 6;
                        qb[(((size_t)(b*QH + h))*T_ + t)*HD_ + hd] = __float2bfloat16(o * QS);
                    } else {
                        int hd = (col - 1024) & 127;   // < 64 here
                        float o = val * crow[hd] + rot * srow[hd];
                        int kvh = (col - 1024) >> 7;
                        kbb[(((size_t)(b*KVH + kvh))*T_ + t)*HD_ + hd] = __float2bfloat16(o);
                    }
                }
            }
        }
    } else {
#pragma unroll
        for (int m = 0; m < 4; ++m) {
            int row0 = bm + wr*64 + m*16 + lhi*4;
            int b = row0 >> 11, t0 = row0 & (T_ - 1);
#pragma unroll
            for (int n = 0; n < 2; ++n) {
                int col = bn + wc*32 + n*16 + l15;
                int kvh = (col - 1024) >> 7;
                int hd = ((col - 1024) & 127) - 64;
                short4v pk = { (short)f2bu(acc[m][n][0]), (short)f2bu(acc[m][n][1]),
                               (short)f2bu(acc[m][n][2]), (short)f2bu(acc[m][n][3]) };
                *(short4v*)&vbt[(((size_t)(b*KVH + kvh))*HD_ + hd)*T_ + t0] = pk;
            }
        }
    }
}

// ---------------- Flash attention: KVBLK=128 (two 64-key sub-tiles per barrier pair) ----------
// 8 waves x 16 q-rows, single K/V buffer pair (Ks[2]/Vs[2] sub-tiles, 48KB total).
// Per trip: prefetch next 128 keys into regs; process sub-tile 0 then 1 (QK/softmax/PV,
// Ps reused — same-wave LDS ordering); barrier; ds_write prefetch; barrier.
// Halves the barrier count vs KVBLK=64.
__global__ __launch_bounds__(512) void attn_mfma(const __hip_bfloat16* __restrict__ qb,
                                                 const __hip_bfloat16* __restrict__ kb,
                                                 const __hip_bfloat16* __restrict__ vbt,
                                                 __hip_bfloat16* __restrict__ ob) {
    __shared__ __hip_bfloat16 Ks[2][64*64];   // [key][d]   swizzled, 2x8KB
    __shared__ __hip_bfloat16 Vs[2][64*64];   // [d][key]   swizzled, 2x8KB
    __shared__ __hip_bfloat16 Ps[128*64];     // [qrow][key] swizzled, per-wave rows, 16KB
    char* PsB = (char*)Ps;
    int tid = threadIdx.x;
    int w = tid >> 6, lane = tid & 63;        // w in 0..7
    int l15 = lane & 15, lhi = lane >> 4;
    int bh = blockIdx.y;
    int b = bh >> 4, h = bh & 15;
    int bk = b * KVH + (h >> 2);
    int qt0 = blockIdx.x * 128;

    const __hip_bfloat16* qrow = qb + ((size_t)bh * T_ + qt0 + w*16 + l15) * HD_;
    short8 qf0 = *(const short8*)(qrow + lhi*8);
    short8 qf1 = *(const short8*)(qrow + 32 + lhi*8);

    f32x4 oacc[4] = {};          // O^T[d=cb*16+lhi*4+r][qrow=l15]
    f32x4 lacc = {};             // l for qrow=l15 (all regs identical)
    float m_run = -INFINITY;     // running max in log2 units
    const short ONE_BF = (short)0x3F80;   // bf16 1.0
    const short8 onesf = { ONE_BF, ONE_BF, ONE_BF, ONE_BF, ONE_BF, ONE_BF, ONE_BF, ONE_BF };

    int sr  = tid >> 3;                // staging row 0..63 (512 thr, 8 chunks/row)
    int scB = (tid & 7) * 16;          // staging col byte {0,16,..,112}
    int sce = (tid & 7) * 8;           // linear source col (elements)
    const __hip_bfloat16* kbase = kb  + (size_t)bk * T_ * HD_;
    const __hip_bfloat16* vbase = vbt + (size_t)bk * HD_ * T_;

    // prologue: stage keys [0,128) into both sub-tile buffers
#pragma unroll
    for (int c = 0; c < 2; ++c) {
        short8 ra = *(const short8*)(kbase + (size_t)(c*64 + sr)*HD_ + sce);
        short8 rc = *(const short8*)(vbase + (size_t)sr*T_ + c*64 + sce);
        *(short8*)((char*)Ks[c] + KSWZ(sr, scB)) = ra;
        *(short8*)((char*)Vs[c] + KSWZ(sr, scB)) = rc;
    }
    __syncthreads();
    const int NT2 = T_ / 128;

    for (int it = 0; it < NT2; ++it) {
        short8 ra0, rc0, ra1, rc1;
        bool pfv = (it + 1 < NT2);
        if (pfv) {
            int s0n = (it + 1) * 128;
            ra0 = *(const short8*)(kbase + (size_t)(s0n + sr)*HD_ + sce);
            rc0 = *(const short8*)(vbase + (size_t)sr*T_ + s0n + sce);
            ra1 = *(const short8*)(kbase + (size_t)(s0n + 64 + sr)*HD_ + sce);
            rc1 = *(const short8*)(vbase + (size_t)sr*T_ + s0n + 64 + sce);
        }

#pragma unroll
        for (int c = 0; c < 2; ++c) {
            char* KsB = (char*)Ks[c];
            char* VsB = (char*)Vs[c];

            // S^T = K Q^T (scores in log2 units)
            f32x4 accs[4];
#pragma unroll
            for (int cb = 0; cb < 4; ++cb) {
                f32x4 z = {0.f, 0.f, 0.f, 0.f};
                short8 k0 = *(const short8*)(KsB + KSWZ(cb*16 + l15, lhi*16));
                short8 k1 = *(const short8*)(KsB + KSWZ(cb*16 + l15, 64 + lhi*16));
                __builtin_amdgcn_s_setprio(1);
                z = __builtin_amdgcn_mfma_f32_16x16x32_bf16(k0, qf0, z, 0, 0, 0);
                z = __builtin_amdgcn_mfma_f32_16x16x32_bf16(k1, qf1, z, 0, 0, 0);
                __builtin_amdgcn_s_setprio(0);
                accs[cb] = z;
            }

            // per-lane local max (no cross-lane reduce in common path)
            float mxl = -INFINITY;
#pragma unroll
            for (int cb = 0; cb < 4; ++cb)
#pragma unroll
                for (int r = 0; r < 4; ++r) mxl = fmaxf(mxl, accs[cb][r]);

            // defer-max (THR=8 in log2 units: P bounded by 2^8)
            if (!__all(mxl <= m_run + 8.0f)) {
                float mx = mxl;
                mx = fmaxf(mx, __shfl_xor(mx, 16));
                mx = fmaxf(mx, __shfl_xor(mx, 32));
                float mn = fmaxf(m_run, mx);
                float cr = EXP2(m_run - mn);
                m_run = mn;
#pragma unroll
                for (int r = 0; r < 4; ++r) lacc[r] *= cr;
#pragma unroll
                for (int cb = 0; cb < 4; ++cb)
#pragma unroll
                    for (int r = 0; r < 4; ++r) oacc[cb][r] *= cr;
            }

            int pr = w*16 + l15;               // per-wave P row (0..127)
#pragma unroll
            for (int cb = 0; cb < 4; ++cb) {
                f32x4 p;
#pragma unroll
                for (int r = 0; r < 4; ++r) p[r] = EXP2(accs[cb][r] - m_run);
                short4v pk = { (short)f2bu(p[0]), (short)f2bu(p[1]),
                               (short)f2bu(p[2]), (short)f2bu(p[3]) };
                *(short4v*)(PsB + KSWZ(pr, cb*32 + lhi*8)) = pk;
            }

            // O^T += V^T P^T ; lacc += ones * P^T
#pragma unroll
            for (int kk = 0; kk < 2; ++kk) {
                short8 pf = *(const short8*)(PsB + KSWZ(w*16 + l15, kk*64 + lhi*16));
                __builtin_amdgcn_s_setprio(1);
                lacc = __builtin_amdgcn_mfma_f32_16x16x32_bf16(onesf, pf, lacc, 0, 0, 0);
#pragma unroll
                for (int cb = 0; cb < 4; ++cb) {
                    short8 vf = *(const short8*)(VsB + KSWZ(cb*16 + l15, kk*64 + lhi*16));
                    oacc[cb] = __builtin_amdgcn_mfma_f32_16x16x32_bf16(vf, pf, oacc[cb], 0, 0, 0);
                }
                __builtin_amdgcn_s_setprio(0);
            }
        }

        __syncthreads();   // all waves done READING Ks/Vs for this 128-key trip
        if (pfv) {
            *(short8*)((char*)Ks[0] + KSWZ(sr, scB)) = ra0;
            *(short8*)((char*)Vs[0] + KSWZ(sr, scB)) = rc0;
            *(short8*)((char*)Ks[1] + KSWZ(sr, scB)) = ra1;
            *(short8*)((char*)Vs[1] + KSWZ(sr, scB)) = rc1;
        }
        __syncthreads();   // writes visible before next trip's reads
    }

    float inv = 1.0f / lacc[0];
    int t = qt0 + w*16 + l15;
    __hip_bfloat16* orow = ob + (size_t)(b*T_ + t) * D_ + h*HD_;
#pragma unroll
    for (int cb = 0; cb < 4; ++cb) {
        short4v okv = { (short)f2bu(oacc[cb][0] * inv), (short)f2bu(oacc[cb][1] * inv),
                        (short)f2bu(oacc[cb][2] * inv), (short)f2bu(oacc[cb][3] * inv) };
        *(short4v*)&orow[cb*16 + lhi*4] = okv;
    }
}

extern "C" void kernel_launch(void* const* d_in, const int* in_sizes, int n_in,
                              void* d_out, int out_size, void* d_ws, size_t ws_size,
                              hipStream_t stream) {
    const float* x    = (const float*)d_in[0];
    const float* cosb = (const float*)d_in[1];
    const float* sinb = (const float*)d_in[2];
    const float* Wq   = (const float*)d_in[3];
    const float* Wkv  = (const float*)d_in[4];
    const float* Wo   = (const float*)d_in[5];
    const float* ln1g = (const float*)d_in[6];
    const float* ln1b = (const float*)d_in[7];
    const float* ln2g = (const float*)d_in[8];
    const float* ln2b = (const float*)d_in[9];
    const float* W1   = (const float*)d_in[10];
    const float* b1   = (const float*)d_in[11];
    const float* W2   = (const float*)d_in[12];
    const float* b2   = (const float*)d_in[13];
    float* out = (float*)d_out;

    float* ws = (float*)d_ws;
    const size_t M = 1024 * 1024;
    __hip_bfloat16* hb   = (__hip_bfloat16*)(ws);
    __hip_bfloat16* x2b  = (__hip_bfloat16*)(ws + 4*M);    // bf16 residual x2
    __hip_bfloat16* gbuf = (__hip_bfloat16*)(ws + 12*M);
    __hip_bfloat16* ob   = (__hip_bfloat16*)(ws + 20*M);
    __hip_bfloat16* qb   = (__hip_bfloat16*)(ws + 24*M);
    __hip_bfloat16* kbb  = (__hip_bfloat16*)(ws + 28*M);
    __hip_bfloat16* vbt  = (__hip_bfloat16*)(ws + 29*M);
    __hip_bfloat16* Wqkvb= (__hip_bfloat16*)(ws + 30*M);
    __hip_bfloat16* Wob  = (__hip_bfloat16*)(ws + 30*M + 3*M/4);
    __hip_bfloat16* W1b  = (__hip_bfloat16*)(ws + 31*M + M/4);
    __hip_bfloat16* W2b  = (__hip_bfloat16*)(ws + 32*M + M/4);

    // 0+1. weight casts + LN1 fused
    prologue_cast_ln<<<6656 + R_, 256, 0, stream>>>(Wq, Wkv, Wo, W1, W2,
                                                    Wqkvb, Wob, W1b, W2b,
                                                    x, ln1g, ln1b, hb);

    // 2+3. qkv GEMM with fused RoPE -> qb/kbb/vbt (bf16), XCD-swizzled 1D grid (768 blocks)
    gemm_qkv_rope<<<(QKVW/128)*(R_/128), 512, 0, stream>>>(hb, Wqkvb, cosb, sinb, qb, kbb, vbt);
    // 4. attention -> ob (bf16), 8-wave blocks, QBLK=128, KVBLK=128, 48KB LDS
    attn_mfma<<<dim3(T_/128, B_*QH), 512, 0, stream>>>(qb, kbb, vbt, ob);
    // 5. x2b = x + ob @ Wob^T (bf16 out, 512 blocks)
    gemm_mfma<1><<<(D_/128)*(R_/128), 512, 0, stream>>>(ob, Wob, nullptr, x, nullptr, nullptr, x2b, R_, D_, D_);
    // 6. LN2 (bf16 in) -> hb (bf16)
    ln_bf16_in<<<R_, 256, 0, stream>>>(x2b, ln2g, ln2b, hb);
    // 7. gbuf = gelu(hb @ W1b^T + b1) (bf16 out, 1024 blocks)
    gemm_mfma<2><<<(DFF/128)*(R_/128), 512, 0, stream>>>(hb, W1b, b1, nullptr, nullptr, nullptr, gbuf, R_, DFF, D_);
    // 8. out = x2b + gbuf @ W2b^T + b2 (f32 out, 512 blocks)
    gemm_mfma<3><<<(D_/128)*(R_/128), 512, 0, stream>>>(gbuf, W2b, b2, nullptr, x2b, out, nullptr, R_, D_, DFF);
}

// Round 28
// 276.237 us; speedup vs baseline: 1.0074x; 1.0074x over previous
//
#include <hip/hip_runtime.h>
#include <hip/hip_bf16.h>
#include <math.h>
#include <stdint.h>

#define B_   4
#define T_   2048
#define D_   1024
#define QH   16
#define KVH  4
#define HD_  64
#define R_   (B_*T_)      // 8192 rows
#define DFF  2048
#define QKVW 1536         // fused q(1024) + kv(512) output width

typedef short short8 __attribute__((ext_vector_type(8)));
typedef short short4v __attribute__((ext_vector_type(4)));
typedef float f32x4 __attribute__((ext_vector_type(4)));

// native exp2 (bare v_exp_f32); guarded fallback is mathematically identical
#if __has_builtin(__builtin_amdgcn_exp2f)
#define EXP2(x) __builtin_amdgcn_exp2f(x)
#else
#define EXP2(x) __expf((x) * 0.6931471805599453f)
#endif

static __device__ __forceinline__ unsigned short f2bu(float x) {
    __hip_bfloat16 h = __float2bfloat16(x);
    return *reinterpret_cast<unsigned short*>(&h);
}
static __device__ __forceinline__ float bu2f(unsigned short u) {
    unsigned int w = ((unsigned int)u) << 16;
    return *reinterpret_cast<float*>(&w);
}

// swizzled byte offset within a 128B/row LDS tile (8-row XOR stripe)
#define KSWZ(row, cbyte) (((row) << 7) + ((cbyte) ^ (((row) & 7) << 4)))

__device__ __forceinline__ void gload_lds16(const void* g, void* l) {
    typedef __attribute__((address_space(1))) void gv_t;
    typedef __attribute__((address_space(3))) void lv_t;
    __builtin_amdgcn_global_load_lds((gv_t*)g, (lv_t*)l, 16, 0, 0);
}

// XCD-aware linear block swizzle (requires nwg % 8 == 0)
__device__ __forceinline__ int xcd_swz(int bid, int nwg) {
    int cpx = nwg >> 3;
    return (bid & 7) * cpx + (bid >> 3);
}

// fast GELU (tanh form) in exp2 domain
__device__ __forceinline__ float gelu_fast(float x) {
    float g2 = 2.3024523389544817f * (x + 0.044715f * x * x * x);
    return x / (1.0f + EXP2(-g2));
}

// ---------------- prologue: weight casts (blocks [0,6656)) + LN1 (blocks [6656,14848)) --------
__global__ __launch_bounds__(256) void prologue_cast_ln(const float* __restrict__ Wq,
                                                        const float* __restrict__ Wkv,
                                                        const float* __restrict__ Wo,
                                                        const float* __restrict__ W1,
                                                        const float* __restrict__ W2,
                                                        __hip_bfloat16* __restrict__ dqkv,
                                                        __hip_bfloat16* __restrict__ dWo,
                                                        __hip_bfloat16* __restrict__ dW1,
                                                        __hip_bfloat16* __restrict__ dW2,
                                                        const float* __restrict__ x,
                                                        const float* __restrict__ g,
                                                        const float* __restrict__ bta,
                                                        __hip_bfloat16* __restrict__ hb) {
    int tid = threadIdx.x;
    if (blockIdx.x < 6656) {
        int i = blockIdx.x * 256 + tid;   // quad index, total exactly 6656*256 = 1703936
        const float* src; __hip_bfloat16* dst; int off;
        if (i < 262144)       { src = Wq;  dst = dqkv;            off = i; }
        else if (i < 393216)  { src = Wkv; dst = dqkv + 1048576;  off = i - 262144; }
        else if (i < 655360)  { src = Wo;  dst = dWo;             off = i - 393216; }
        else if (i < 1179648) { src = W1;  dst = dW1;             off = i - 655360; }
        else                  { src = W2;  dst = dW2;             off = i - 1179648; }
        float4 v = *(const float4*)&src[(size_t)off*4];
        ushort4 o = { f2bu(v.x), f2bu(v.y), f2bu(v.z), f2bu(v.w) };
        *(ushort4*)&dst[(size_t)off*4] = o;
        return;
    }
    int row = blockIdx.x - 6656;
    const float* xr = x + (size_t)row * D_;
    int c = tid * 4;
    float4 v = *(const float4*)&xr[c];
    float s = v.x + v.y + v.z + v.w;
#pragma unroll
    for (int off = 32; off >= 1; off >>= 1) s += __shfl_xor(s, off);
    __shared__ float sm[4], sv[4];
    int wid = tid >> 6, lane = tid & 63;
    if (lane == 0) sm[wid] = s;
    __syncthreads();
    float mean = (sm[0] + sm[1] + sm[2] + sm[3]) * (1.0f / D_);
    float d0 = v.x - mean, d1 = v.y - mean, d2 = v.z - mean, d3 = v.w - mean;
    float qq = d0*d0 + d1*d1 + d2*d2 + d3*d3;
#pragma unroll
    for (int off = 32; off >= 1; off >>= 1) qq += __shfl_xor(qq, off);
    if (lane == 0) sv[wid] = qq;
    __syncthreads();
    float var = (sv[0] + sv[1] + sv[2] + sv[3]) * (1.0f / D_);
    float rstd = rsqrtf(var + 1e-5f);
    float4 gg = *(const float4*)&g[c];
    float4 bb = *(const float4*)&bta[c];
    ushort4 o = { f2bu(d0 * rstd * gg.x + bb.x),
                  f2bu(d1 * rstd * gg.y + bb.y),
                  f2bu(d2 * rstd * gg.z + bb.z),
                  f2bu(d3 * rstd * gg.w + bb.w) };
    *(ushort4*)&(hb + (size_t)row * D_)[c] = o;
}

// ---------------- LayerNorm with bf16 input -> bf16 out: one block per row ----------------
__global__ __launch_bounds__(256) void ln_bf16_in(const __hip_bfloat16* __restrict__ x,
                                                  const float* __restrict__ g,
                                                  const float* __restrict__ bta,
                                                  __hip_bfloat16* __restrict__ out) {
    int row = blockIdx.x;
    int tid = threadIdx.x;
    const __hip_bfloat16* xr = x + (size_t)row * D_;
    int c = tid * 4;
    ushort4 u = *(const ushort4*)&xr[c];
    float v0 = bu2f(u.x), v1 = bu2f(u.y), v2 = bu2f(u.z), v3 = bu2f(u.w);
    float s = v0 + v1 + v2 + v3;
#pragma unroll
    for (int off = 32; off >= 1; off >>= 1) s += __shfl_xor(s, off);
    __shared__ float sm[4], sv[4];
    int wid = tid >> 6, lane = tid & 63;
    if (lane == 0) sm[wid] = s;
    __syncthreads();
    float mean = (sm[0] + sm[1] + sm[2] + sm[3]) * (1.0f / D_);
    float d0 = v0 - mean, d1 = v1 - mean, d2 = v2 - mean, d3 = v3 - mean;
    float qq = d0*d0 + d1*d1 + d2*d2 + d3*d3;
#pragma unroll
    for (int off = 32; off >= 1; off >>= 1) qq += __shfl_xor(qq, off);
    if (lane == 0) sv[wid] = qq;
    __syncthreads();
    float var = (sv[0] + sv[1] + sv[2] + sv[3]) * (1.0f / D_);
    float rstd = rsqrtf(var + 1e-5f);
    float4 gg = *(const float4*)&g[c];
    float4 bb = *(const float4*)&bta[c];
    ushort4 o = { f2bu(d0 * rstd * gg.x + bb.x),
                  f2bu(d1 * rstd * gg.y + bb.y),
                  f2bu(d2 * rstd * gg.z + bb.z),
                  f2bu(d3 * rstd * gg.w + bb.w) };
    *(ushort4*)&(out + (size_t)row * D_)[c] = o;
}

// ---------------- bf16 MFMA GEMM, BK=64, swizzled LDS, 8 waves (wave-tile 64x32) --------------
// MODE 1: += res(f32), out bf16 Cb; MODE 2: += bias, gelu, out bf16 Cb;
// MODE 3: += bias, += resb(bf16), out f32 Cf
template<int MODE>
__global__ __launch_bounds__(512) void gemm_mfma(const __hip_bfloat16* __restrict__ A,
                                                 const __hip_bfloat16* __restrict__ W,
                                                 const float* __restrict__ bias,
                                                 const float* __restrict__ res,
                                                 const __hip_bfloat16* __restrict__ resb,
                                                 float* __restrict__ Cf,
                                                 __hip_bfloat16* __restrict__ Cb,
                                                 int M, int N, int K) {
    __shared__ __hip_bfloat16 At[128*64];
    __shared__ __hip_bfloat16 Bt[128*64];
    int tid = threadIdx.x;
    int w = tid >> 6, lane = tid & 63;        // w in 0..7
    int l15 = lane & 15, lhi = lane >> 4;
    int swz = xcd_swz(blockIdx.x, gridDim.x);
    int gx = N >> 7;
    int bn = (swz % gx) * 128, bm = (swz / gx) * 128;
    int wr = w >> 2, wc = w & 3;              // wave tile 64(M) x 32(N)
    f32x4 acc[4][2] = {};

    for (int k0 = 0; k0 < K; k0 += 64) {
#pragma unroll
        for (int iss = 0; iss < 2; ++iss) {
            int idx = iss*512 + tid;               // 0..1023
            int row = idx >> 3;                    // 0..127
            int cb  = (idx & 7) * 16;              // byte col within 128B row
            int sce = (cb ^ ((row & 7) << 4)) >> 1;  // pre-swizzled source col (elements)
            int ldso = idx * 16;                   // linear LDS byte offset
            gload_lds16(A + (size_t)(bm + row) * K + k0 + sce, (char*)At + ldso);
            gload_lds16(W + (size_t)(bn + row) * K + k0 + sce, (char*)Bt + ldso);
        }
        __syncthreads();
#pragma unroll
        for (int kk = 0; kk < 2; ++kk) {
            short8 af[4], bf[2];
#pragma unroll
            for (int m = 0; m < 4; ++m)
                af[m] = *(const short8*)((char*)At + KSWZ(wr*64 + m*16 + l15, kk*64 + lhi*16));
#pragma unroll
            for (int n = 0; n < 2; ++n)
                bf[n] = *(const short8*)((char*)Bt + KSWZ(wc*32 + n*16 + l15, kk*64 + lhi*16));
#pragma unroll
            for (int m = 0; m < 4; ++m)
#pragma unroll
                for (int n = 0; n < 2; ++n)
                    acc[m][n] = __builtin_amdgcn_mfma_f32_16x16x32_bf16(af[m], bf[n], acc[m][n], 0, 0, 0);
        }
        __syncthreads();
    }

#pragma unroll
    for (int m = 0; m < 4; ++m) {
#pragma unroll
        for (int j = 0; j < 4; ++j) {
            int row = bm + wr*64 + m*16 + lhi*4 + j;
#pragma unroll
            for (int n = 0; n < 2; ++n) {
                int col = bn + wc*32 + n*16 + l15;
                float val = acc[m][n][j];
                if (MODE == 2 || MODE == 3) val += bias[col];
                if (MODE == 2) val = gelu_fast(val);
                if (MODE == 1) val += res[(size_t)row * N + col];
                if (MODE == 3) val += bu2f(*(const unsigned short*)&resb[(size_t)row * N + col]);
                if (MODE == 3) Cf[(size_t)row * N + col] = val;
                else           Cb[(size_t)row * N + col] = __float2bfloat16(val);
            }
        }
    }
}

// ---------------- QKV GEMM with fused RoPE epilogue (8 waves, wave-tile 64x32) ----------------
// q is pre-scaled by (1/8)*log2e so attention scores land in the exp2 domain.
__global__ __launch_bounds__(512) void gemm_qkv_rope(const __hip_bfloat16* __restrict__ A,
                                                     const __hip_bfloat16* __restrict__ W,
                                                     const float* __restrict__ cosb,
                                                     const float* __restrict__ sinb,
                                                     __hip_bfloat16* __restrict__ qb,
                                                     __hip_bfloat16* __restrict__ kbb,
                                                     __hip_bfloat16* __restrict__ vbt) {
    const int K = D_;
    const float QS = 0.125f * 1.4426950408889634f;
    __shared__ __hip_bfloat16 At[128*64];
    __shared__ __hip_bfloat16 Bt[128*64];
    int tid = threadIdx.x;
    int w = tid >> 6, lane = tid & 63;        // w in 0..7
    int l15 = lane & 15, lhi = lane >> 4;
    int swz = xcd_swz(blockIdx.x, gridDim.x);
    const int gx = QKVW >> 7;   // 12
    int bn = (swz % gx) * 128, bm = (swz / gx) * 128;
    int wr = w >> 2, wc = w & 3;              // wave tile 64(M) x 32(N)
    f32x4 acc[4][2] = {};

    for (int k0 = 0; k0 < K; k0 += 64) {
#pragma unroll
        for (int iss = 0; iss < 2; ++iss) {
            int idx = iss*512 + tid;
            int row = idx >> 3;
            int cb  = (idx & 7) * 16;
            int sce = (cb ^ ((row & 7) << 4)) >> 1;
            int ldso = idx * 16;
            gload_lds16(A + (size_t)(bm + row) * K + k0 + sce, (char*)At + ldso);
            gload_lds16(W + (size_t)(bn + row) * K + k0 + sce, (char*)Bt + ldso);
        }
        __syncthreads();
#pragma unroll
        for (int kk = 0; kk < 2; ++kk) {
            short8 af[4], bf[2];
#pragma unroll
            for (int m = 0; m < 4; ++m)
                af[m] = *(const short8*)((char*)At + KSWZ(wr*64 + m*16 + l15, kk*64 + lhi*16));
#pragma unroll
            for (int n = 0; n < 2; ++n)
                bf[n] = *(const short8*)((char*)Bt + KSWZ(wc*32 + n*16 + l15, kk*64 + lhi*16));
#pragma unroll
            for (int m = 0; m < 4; ++m)
#pragma unroll
                for (int n = 0; n < 2; ++n)
                    acc[m][n] = __builtin_amdgcn_mfma_f32_16x16x32_bf16(af[m], bf[n], acc[m][n], 0, 0, 0);
        }
        __syncthreads();
    }

    bool is_q = (bn < 1024);
    bool is_v = (!is_q) && (wc >= 2);   // wave-uniform (v = upper 64 cols of kv tile)
    if (!is_v) {
#pragma unroll
        for (int m = 0; m < 4; ++m) {
#pragma unroll
            for (int j = 0; j < 4; ++j) {
                int row = bm + wr*64 + m*16 + lhi*4 + j;
                int b = row >> 11, t = row & (T_ - 1);
                const float* crow = cosb + t*HD_;
                const float* srow = sinb + t*HD_;
#pragma unroll
                for (int n = 0; n < 2; ++n) {
                    int col = bn + wc*32 + n*16 + l15;
                    float val = acc[m][n][j];
                    float part = __shfl_xor(val, 1);
                    float rot = (l15 & 1) ? part : -part;
                    if (is_q) {
                        int hd = col & 63;
                        float o = val * crow[hd] + rot * srow[hd];
                        int h = col >> 6;
                        qb[(((size_t)(b*QH + h))*T_ + t)*HD_ + hd] = __float2bfloat16(o * QS);
                    } else {
                        int hd = (col - 1024) & 127;   // < 64 here
                        float o = val * crow[hd] + rot * srow[hd];
                        int kvh = (col - 1024) >> 7;
                        kbb[(((size_t)(b*KVH + kvh))*T_ + t)*HD_ + hd] = __float2bfloat16(o);
                    }
                }
            }
        }
    } else {
#pragma unroll
        for (int m = 0; m < 4; ++m) {
            int row0 = bm + wr*64 + m*16 + lhi*4;
            int b = row0 >> 11, t0 = row0 & (T_ - 1);
#pragma unroll
            for (int n = 0; n < 2; ++n) {
                int col = bn + wc*32 + n*16 + l15;
                int kvh = (col - 1024) >> 7;
                int hd = ((col - 1024) & 127) - 64;
                short4v pk = { (short)f2bu(acc[m][n][0]), (short)f2bu(acc[m][n][1]),
                               (short)f2bu(acc[m][n][2]), (short)f2bu(acc[m][n][3]) };
                *(short4v*)&vbt[(((size_t)(b*KVH + kvh))*HD_ + hd)*T_ + t0] = pk;
            }
        }
    }
}

// ---------------- Flash attention: R25/R26 structure (best measured 95.6us) ----------------
__global__ __launch_bounds__(512) void attn_mfma(const __hip_bfloat16* __restrict__ qb,
                                                 const __hip_bfloat16* __restrict__ kb,
                                                 const __hip_bfloat16* __restrict__ vbt,
                                                 __hip_bfloat16* __restrict__ ob) {
    __shared__ __hip_bfloat16 Ks[64*64];      // [key][d]   swizzled, 8KB
    __shared__ __hip_bfloat16 Vs[64*64];      // [d][key]   swizzled, 8KB
    __shared__ __hip_bfloat16 Ps[128*64];     // [qrow][key] swizzled, per-wave rows, 16KB
    char* PsB = (char*)Ps;
    char* KsB = (char*)Ks;
    char* VsB = (char*)Vs;
    int tid = threadIdx.x;
    int w = tid >> 6, lane = tid & 63;        // w in 0..7
    int l15 = lane & 15, lhi = lane >> 4;
    int bh = blockIdx.y;
    int b = bh >> 4, h = bh & 15;
    int bk = b * KVH + (h >> 2);
    int qt0 = blockIdx.x * 128;

    const __hip_bfloat16* qrow = qb + ((size_t)bh * T_ + qt0 + w*16 + l15) * HD_;
    short8 qf0 = *(const short8*)(qrow + lhi*8);
    short8 qf1 = *(const short8*)(qrow + 32 + lhi*8);

    f32x4 oacc[4] = {};          // O^T[d=cb*16+lhi*4+r][qrow=l15]
    f32x4 lacc = {};             // l for qrow=l15 (all regs identical)
    float m_run = -INFINITY;     // running max in log2 units
    const short ONE_BF = (short)0x3F80;   // bf16 1.0
    const short8 onesf = { ONE_BF, ONE_BF, ONE_BF, ONE_BF, ONE_BF, ONE_BF, ONE_BF, ONE_BF };

    int sr  = tid >> 3;                // staging row 0..63 (512 thr, 8 chunks/row)
    int scB = (tid & 7) * 16;          // staging col byte {0,16,..,112}
    int sce = (tid & 7) * 8;           // linear source col (elements)
    const __hip_bfloat16* kbase = kb  + (size_t)bk * T_ * HD_;
    const __hip_bfloat16* vbase = vbt + (size_t)bk * HD_ * T_;

    // prologue: stage tile 0
    {
        short8 ra = *(const short8*)(kbase + (size_t)sr*HD_ + sce);
        short8 rc = *(const short8*)(vbase + (size_t)sr*T_ + sce);
        *(short8*)(KsB + KSWZ(sr, scB)) = ra;
        *(short8*)(VsB + KSWZ(sr, scB)) = rc;
    }
    __syncthreads();
    const int NT = T_ / 64;

    for (int it = 0; it < NT; ++it) {
        short8 ra, rc;
        bool pfv = (it + 1 < NT);
        if (pfv) {
            int s0n = (it + 1) * 64;
            ra = *(const short8*)(kbase + (size_t)(s0n + sr)*HD_ + sce);
            rc = *(const short8*)(vbase + (size_t)sr*T_ + s0n + sce);
        }

        // S^T = K Q^T (scores in log2 units)
        f32x4 accs[4];
#pragma unroll
        for (int cb = 0; cb < 4; ++cb) {
            f32x4 z = {0.f, 0.f, 0.f, 0.f};
            short8 k0 = *(const short8*)(KsB + KSWZ(cb*16 + l15, lhi*16));
            short8 k1 = *(const short8*)(KsB + KSWZ(cb*16 + l15, 64 + lhi*16));
            __builtin_amdgcn_s_setprio(1);
            z = __builtin_amdgcn_mfma_f32_16x16x32_bf16(k0, qf0, z, 0, 0, 0);
            z = __builtin_amdgcn_mfma_f32_16x16x32_bf16(k1, qf1, z, 0, 0, 0);
            __builtin_amdgcn_s_setprio(0);
            accs[cb] = z;
        }

        // per-lane local max (no cross-lane reduce in common path)
        float mxl = -INFINITY;
#pragma unroll
        for (int cb = 0; cb < 4; ++cb)
#pragma unroll
            for (int r = 0; r < 4; ++r) mxl = fmaxf(mxl, accs[cb][r]);

        // defer-max (THR=8 in log2 units: P bounded by 2^8)
        if (!__all(mxl <= m_run + 8.0f)) {
            float mx = mxl;
            mx = fmaxf(mx, __shfl_xor(mx, 16));
            mx = fmaxf(mx, __shfl_xor(mx, 32));
            float mn = fmaxf(m_run, mx);
            float cr = EXP2(m_run - mn);
            m_run = mn;
#pragma unroll
            for (int r = 0; r < 4; ++r) lacc[r] *= cr;
#pragma unroll
            for (int cb = 0; cb < 4; ++cb)
#pragma unroll
                for (int r = 0; r < 4; ++r) oacc[cb][r] *= cr;
        }

        int pr = w*16 + l15;               // per-wave P row (0..127)
#pragma unroll
        for (int cb = 0; cb < 4; ++cb) {
            f32x4 p;
#pragma unroll
            for (int r = 0; r < 4; ++r) p[r] = EXP2(accs[cb][r] - m_run);
            short4v pk = { (short)f2bu(p[0]), (short)f2bu(p[1]),
                           (short)f2bu(p[2]), (short)f2bu(p[3]) };
            *(short4v*)(PsB + KSWZ(pr, cb*32 + lhi*8)) = pk;
        }

        // O^T += V^T P^T ; lacc += ones * P^T
#pragma unroll
        for (int kk = 0; kk < 2; ++kk) {
            short8 pf = *(const short8*)(PsB + KSWZ(w*16 + l15, kk*64 + lhi*16));
            __builtin_amdgcn_s_setprio(1);
            lacc = __builtin_amdgcn_mfma_f32_16x16x32_bf16(onesf, pf, lacc, 0, 0, 0);
#pragma unroll
            for (int cb = 0; cb < 4; ++cb) {
                short8 vf = *(const short8*)(VsB + KSWZ(cb*16 + l15, kk*64 + lhi*16));
                oacc[cb] = __builtin_amdgcn_mfma_f32_16x16x32_bf16(vf, pf, oacc[cb], 0, 0, 0);
            }
            __builtin_amdgcn_s_setprio(0);
        }

        __syncthreads();   // all waves done READING Ks/Vs for this tile
        if (pfv) {
            *(short8*)(KsB + KSWZ(sr, scB)) = ra;   // overwrite same buffer
            *(short8*)(VsB + KSWZ(sr, scB)) = rc;
        }
        __syncthreads();   // writes visible before next tile's reads
    }

    float inv = 1.0f / lacc[0];
    int t = qt0 + w*16 + l15;
    __hip_bfloat16* orow = ob + (size_t)(b*T_ + t) * D_ + h*HD_;
#pragma unroll
    for (int cb = 0; cb < 4; ++cb) {
        short4v okv = { (short)f2bu(oacc[cb][0] * inv), (short)f2bu(oacc[cb][1] * inv),
                        (short)f2bu(oacc[cb][2] * inv), (short)f2bu(oacc[cb][3] * inv) };
        *(short4v*)&orow[cb*16 + lhi*4] = okv;
    }
}

extern "C" void kernel_launch(void* const* d_in, const int* in_sizes, int n_in,
                              void* d_out, int out_size, void* d_ws, size_t ws_size,
                              hipStream_t stream) {
    const float* x    = (const float*)d_in[0];
    const float* cosb = (const float*)d_in[1];
    const float* sinb = (const float*)d_in[2];
    const float* Wq   = (const float*)d_in[3];
    const float* Wkv  = (const float*)d_in[4];
    const float* Wo   = (const float*)d_in[5];
    const float* ln1g = (const float*)d_in[6];
    const float* ln1b = (const float*)d_in[7];
    const float* ln2g = (const float*)d_in[8];
    const float* ln2b = (const float*)d_in[9];
    const float* W1   = (const float*)d_in[10];
    const float* b1   = (const float*)d_in[11];
    const float* W2   = (const float*)d_in[12];
    const float* b2   = (const float*)d_in[13];
    float* out = (float*)d_out;

    float* ws = (float*)d_ws;
    const size_t M = 1024 * 1024;
    __hip_bfloat16* hb   = (__hip_bfloat16*)(ws);
    __hip_bfloat16* x2b  = (__hip_bfloat16*)(ws + 4*M);    // bf16 residual x2
    __hip_bfloat16* gbuf = (__hip_bfloat16*)(ws + 12*M);
    __hip_bfloat16* ob   = (__hip_bfloat16*)(ws + 20*M);
    __hip_bfloat16* qb   = (__hip_bfloat16*)(ws + 24*M);
    __hip_bfloat16* kbb  = (__hip_bfloat16*)(ws + 28*M);
    __hip_bfloat16* vbt  = (__hip_bfloat16*)(ws + 29*M);
    __hip_bfloat16* Wqkvb= (__hip_bfloat16*)(ws + 30*M);
    __hip_bfloat16* Wob  = (__hip_bfloat16*)(ws + 30*M + 3*M/4);
    __hip_bfloat16* W1b  = (__hip_bfloat16*)(ws + 31*M + M/4);
    __hip_bfloat16* W2b  = (__hip_bfloat16*)(ws + 32*M + M/4);

    // 0+1. weight casts + LN1 fused
    prologue_cast_ln<<<6656 + R_, 256, 0, stream>>>(Wq, Wkv, Wo, W1, W2,
                                                    Wqkvb, Wob, W1b, W2b,
                                                    x, ln1g, ln1b, hb);

    // 2+3. qkv GEMM with fused RoPE -> qb/kbb/vbt (bf16), XCD-swizzled 1D grid (768 blocks)
    gemm_qkv_rope<<<(QKVW/128)*(R_/128), 512, 0, stream>>>(hb, Wqkvb, cosb, sinb, qb, kbb, vbt);
    // 4. attention -> ob (bf16), 8-wave blocks, QBLK=128, 32KB LDS
    attn_mfma<<<dim3(T_/128, B_*QH), 512, 0, stream>>>(qb, kbb, vbt, ob);
    // 5. x2b = x + ob @ Wob^T (bf16 out, 512 blocks)
    gemm_mfma<1><<<(D_/128)*(R_/128), 512, 0, stream>>>(ob, Wob, nullptr, x, nullptr, nullptr, x2b, R_, D_, D_);
    // 6. LN2 (bf16 in) -> hb (bf16)
    ln_bf16_in<<<R_, 256, 0, stream>>>(x2b, ln2g, ln2b, hb);
    // 7. gbuf = gelu(hb @ W1b^T + b1) (bf16 out, 1024 blocks)
    gemm_mfma<2><<<(DFF/128)*(R_/128), 512, 0, stream>>>(hb, W1b, b1, nullptr, nullptr, nullptr, gbuf, R_, DFF, D_);
    // 8. out = x2b + gbuf @ W2b^T + b2 (f32 out, 512 blocks)
    gemm_mfma<3><<<(D_/128)*(R_/128), 512, 0, stream>>>(gbuf, W2b, b2, nullptr, x2b, out, nullptr, R_, D_, DFF);
}